// Round 14
// baseline (2213.489 us; speedup 1.0000x reference)
//
#include <hip/hip_runtime.h>
#include <hip/hip_fp16.h>

// ws layout (floats)
#define WS_GX   0                       // 4096: Gx[cp][c] = alpha*sum_o wk[o][c]*wq[o][cp]
#define WS_CPV  4096                    // 4096: Cpvx[c][o] = sum_m wp[o][m]*wv[m][c]
#define WS_QB   8192                    // 64:   alpha * Wk^T bq
#define WS_BPV  8256                    // 64:   Wp bv + bp
#define WS_C2   8448                    // 4096*1536 conv2 output (flattened fc input)
#define WS_Z1   (8448 + 4096*1536)      // 4096*768 fc1 output

// ---------------- K0: tiny precompute of fused weight products ----------------
__global__ void k0_precompute(const float* __restrict__ wq, const float* __restrict__ bq,
                              const float* __restrict__ wk, const float* __restrict__ bk,
                              const float* __restrict__ wv, const float* __restrict__ bv,
                              const float* __restrict__ wp, const float* __restrict__ bp,
                              float* __restrict__ ws) {
  int idx = blockIdx.x * 256 + threadIdx.x;
  const float ALPHA = 0.125f * 1.4426950408889634f;  // C^-0.5 * log2(e), folded into scores
  if (idx < 4096) {
    int cp = idx >> 6, c = idx & 63;
    float s = 0.f;
    for (int o = 0; o < 64; ++o) s += wk[o*64 + c] * wq[o*64 + cp];
    ws[WS_GX + idx] = s * ALPHA;
  } else if (idx < 8192) {
    int i = idx - 4096; int c = i >> 6, o = i & 63;
    float s = 0.f;
    for (int m = 0; m < 64; ++m) s += wp[o*64 + m] * wv[m*64 + c];
    ws[WS_CPV + i] = s;
  } else if (idx < 8256) {
    int c = idx - 8192;
    float s = 0.f;
    for (int o = 0; o < 64; ++o) s += wk[o*64 + c] * bq[o];
    ws[WS_QB + c] = s * ALPHA;
  } else if (idx < 8320) {
    int o = idx - 8256;
    float s = bp[o];
    for (int m = 0; m < 64; ++m) s += wp[o*64 + m] * bv[m];
    ws[WS_BPV + o] = s;
  }
}

// xor8 cross-lane add via DPP row_ror:8 — VALU pipe (verified r12).
__device__ __forceinline__ int xor8_dpp_i(int v) {
  return __builtin_amdgcn_update_dpp(0, v, 0x128, 0xF, 0xF, true);
}
__device__ __forceinline__ __half2 h2_comb(__half2 v) {
  int i0 = *(int*)&v;
  int r8 = xor8_dpp_i(i0);
  __half2 a = v; __half2 b; *(int*)&b = r8;
  __half2 s = __hadd2(a, b);
  int i1 = *(int*)&s;
  int r16 = __shfl_xor(i1, 16);
  __half2 c2; *(int*)&c2 = r16;
  return __hadd2(s, c2);
}

// fp32 Hs layout: slot = c*192 + (u&~31)|((u&31) ^ ROT(c>>4)), ROT(q)=q*8. Lane map r12:
// qg=(l>>3)&3 (bits 3,4), j = w*16+(l&7)+((l>>5)<<3). Verified r10-r12.
//
// r13 fp16-packed attention gave k1 2150->2040us but the counters exposed two pack-stage
// regressions: spill doubled (v[32] staged across a barrier) and conflicts x8.5 (all
// pack accesses had c varying across lanes with c*192 = c*96 = 0 mod 32 -> 16-way).
// r14 FIX (pack stage only; attention loop identical): packed region moved to the
// SECOND half of Hs (word 6144+) so only fp32 channels 32..63 are clobbered. Each
// thread packs 8 words of one ch>=32 (staged, v[16]) + 8 words of one ch<32 (read
// direct after barrier from the never-written first half). Per-thread word window
// wo = (tt%12)*8 spreads banks.
__launch_bounds__(384, 4)
__global__ void k1_sample(const float* __restrict__ x,
                          const float* __restrict__ w1, const float* __restrict__ b1,
                          const float* __restrict__ chw, const float* __restrict__ chb,
                          const float* __restrict__ gnw, const float* __restrict__ gnb,
                          const float* __restrict__ ch2w, const float* __restrict__ ch2b,
                          const float* __restrict__ ws, float* __restrict__ c2out) {
  __shared__ __align__(16) float Hs[64 * 192];
  __shared__ float redS[384];
  __shared__ float redQ[384];
  __shared__ float scS[64];
  __shared__ float shS[64];

  const int tt   = threadIdx.x;        // 0..383
  const int b    = blockIdx.x;         // sample
  const int w    = tt >> 6;            // wave 0..5
  const int l    = tt & 63;
  const int qg   = (l >> 3) & 3;       // channel quarter 0..3 (lane bits 3,4)
  const int c0   = qg << 4;            // channel base
  const int rot  = qg << 3;            // fp32 token rotation for own channels
  const int j    = w * 16 + (l & 7) + ((l >> 5) << 3);  // token-pair id 0..95
  const int t0   = j;                  // tokens owned by this thread
  const int t1   = j + 96;
  const int p0   = (t0 & ~31) | ((t0 & 31) ^ rot);
  const int p1   = (t1 & ~31) | ((t1 & 31) ^ rot);

  const float x0 = x[b*3+0], x1 = x[b*3+1], x2 = x[b*3+2];

  auto make_hv = [&](int t, float* hv) {
    int y = t >> 6, xx = t & 63;
    #pragma unroll
    for (int dy = 0; dy < 3; ++dy) {
      int r = y + dy - 1;
      bool rv = (r >= 0) && (r < 3);
      float xr = (r == 0) ? x0 : ((r == 1) ? x1 : x2);
      #pragma unroll
      for (int dx = 0; dx < 3; ++dx) {
        int cc = xx + dx - 1;
        bool cv = (cc >= 0) && (cc < 64);
        float w1v = cv ? w1[cc] : 0.f;
        float b1v = cv ? b1[cc] : 0.f;
        hv[dy*3+dx] = rv ? fmaf(xr, w1v, b1v) : 0.f;
      }
    }
  };

  // conv1 (1->64): own 16 channels at tokens t0, t1
  {
    float hv[9];
    make_hv(t0, hv);
    #pragma unroll
    for (int i = 0; i < 16; ++i) {
      int c = c0 + i;
      float acc = chb[c];
      #pragma unroll
      for (int q = 0; q < 9; ++q) acc = fmaf(chw[c*9+q], hv[q], acc);
      Hs[c*192 + p0] = acc;
    }
    make_hv(t1, hv);
    #pragma unroll
    for (int i = 0; i < 16; ++i) {
      int c = c0 + i;
      float acc = chb[c];
      #pragma unroll
      for (int q = 0; q < 9; ++q) acc = fmaf(chw[c*9+q], hv[q], acc);
      Hs[c*192 + p1] = acc;
    }
  }
  __syncthreads();

  // instance-norm stats
  {
    int c = tt & 63, seg = tt >> 6;
    int rc = (c >> 4) << 3;
    int base = c*192 + seg*32;
    float s = 0.f, q = 0.f;
    for (int u = 0; u < 32; ++u) {
      float v = Hs[base + (((u + c) & 31) ^ rc)];
      s += v; q = fmaf(v, v, q);
    }
    redS[tt] = s; redQ[tt] = q;
  }
  __syncthreads();
  if (tt < 64) {
    float s = 0.f, q = 0.f;
    #pragma unroll
    for (int i = 0; i < 6; ++i) { s += redS[i*64 + tt]; q += redQ[i*64 + tt]; }
    float mu  = s * (1.f/192.f);
    float var = q * (1.f/192.f) - mu*mu;
    float rs  = rsqrtf(var + 1e-5f);
    float sc  = gnw[tt] * rs;
    scS[tt] = sc;
    shS[tt] = gnb[tt] - mu * sc;
  }
  __syncthreads();
  // normalize in place (own 16 channels at t0, t1)
  #pragma unroll
  for (int i = 0; i < 16; ++i) {
    int c = c0 + i;
    float sc = scS[c], sh = shS[c];
    Hs[c*192 + p0] = fmaf(Hs[c*192 + p0], sc, sh);
    Hs[c*192 + p1] = fmaf(Hs[c*192 + p1], sc, sh);
  }
  __syncthreads();

  // ---- pack normalized h into half2 in the SECOND half of Hs (word 6144+) ----
  // Hp[c*96 + kp], kp = (k&~15)|((k&15)^((c>>4)<<2)); word k = tokens (2k, 2k+1).
  // Thread tt: channel pair (32+cl, cl), cl = tt/12, words wo..wo+7, wo = (tt%12)*8.
  // ch>=32 fp32 data lives where packed words land -> staged in v[16] before barrier;
  // ch<32 fp32 (first half) is never overwritten -> read direct after barrier.
  unsigned int* Hp = (unsigned int*)Hs + 6144;
  {
    const int cl = tt / 12;            // 0..31
    const int wo = (tt - cl*12) * 8;   // 0..88
    float v[16];
    {
      int c = 32 + cl;
      int rc = (c >> 4) << 3;
      #pragma unroll
      for (int kk = 0; kk < 8; ++kk) {
        int tok = 2*(wo + kk);
        int s0 = (tok & ~31) | ((tok & 31) ^ rc);   // rc even -> slot of tok+1 = s0+1
        v[2*kk]   = Hs[c*192 + s0];
        v[2*kk+1] = Hs[c*192 + s0 + 1];
      }
    }
    __syncthreads();
    {
      int c = 32 + cl;
      int sw = (c >> 4) << 2;
      #pragma unroll
      for (int kk = 0; kk < 8; ++kk) {
        int k = wo + kk;
        int kp = (k & ~15) | ((k & 15) ^ sw);
        __half2 h2v = __floats2half2_rn(v[2*kk], v[2*kk+1]);
        Hp[c*96 + kp] = *(unsigned int*)&h2v;
      }
    }
    {
      int c = cl;
      int rc = (c >> 4) << 3;
      int sw = (c >> 4) << 2;
      #pragma unroll
      for (int kk = 0; kk < 8; ++kk) {
        int tok = 2*(wo + kk);
        int s0 = (tok & ~31) | ((tok & 31) ^ rc);
        float a  = Hs[c*192 + s0];
        float b2 = Hs[c*192 + s0 + 1];
        int k = wo + kk;
        int kp = (k & ~15) | ((k & 15) ^ sw);
        __half2 h2v = __floats2half2_rn(a, b2);
        Hp[c*96 + kp] = *(unsigned int*)&h2v;
      }
    }
  }
  __syncthreads();

  // ---- attention ----
  const float* __restrict__ Gx  = ws + WS_GX;
  const float* __restrict__ qb  = ws + WS_QB;
  const float* __restrict__ Cpv = ws + WS_CPV;
  const float* __restrict__ bpv = ws + WS_BPV;

  // q~ for own 16 channels, both tokens, reading packed h (fp32 accumulation).
  float qtA[16], qtB[16];
  #pragma unroll
  for (int i = 0; i < 16; ++i) { qtA[i] = qb[c0 + i]; qtB[i] = qtA[i]; }
  {
    const int k0A = t0 >> 1;          // t1>>1 = k0A + 48 (48 % 16 == 0 -> same swizzle class)
    const bool hiA = (t0 & 1) != 0;   // t1 has same parity as t0
    for (int gq = 0; gq < 4; ++gq) {
      int kA = (k0A & ~15) | ((k0A & 15) ^ (gq << 2));
      int kB = kA + 48;
      for (int cp = gq*16; cp < gq*16 + 16; ++cp) {
        unsigned int wA = Hp[cp*96 + kA];
        unsigned int wB = Hp[cp*96 + kB];
        __half2 a2; *(unsigned int*)&a2 = wA;
        __half2 b2; *(unsigned int*)&b2 = wB;
        float hA = hiA ? __high2float(a2) : __low2float(a2);
        float hB = hiA ? __high2float(b2) : __low2float(b2);
        const float* gx = Gx + cp*64 + c0;
        #pragma unroll
        for (int i = 0; i < 16; ++i) {
          qtA[i] = fmaf(gx[i], hA, qtA[i]);
          qtB[i] = fmaf(gx[i], hB, qtB[i]);
        }
      }
    }
  }

  // pack q~ into (q,q) half2 for hfma2
  __half2 qpA[16], qpB[16];
  #pragma unroll
  for (int i = 0; i < 16; ++i) {
    qpA[i] = __floats2half2_rn(qtA[i], qtA[i]);
    qpB[i] = __floats2half2_rn(qtB[i], qtB[i]);
  }

  // no-max softmax (|s| << 1, r11-verified) + g = attn @ h, packed half2.
  const __half2 h2z = __floats2half2_rn(0.f, 0.f);
  __half2 gpA[16], gpB[16];
  #pragma unroll
  for (int i = 0; i < 16; ++i) { gpA[i] = h2z; gpB[i] = h2z; }
  float lA = 0.f, lB = 0.f;
  for (int u0 = 0; u0 < 192; u0 += 8) {
    const int k  = u0 >> 1;                          // 4-aligned
    const int kp = (k & ~15) | ((k & 15) ^ (qg << 2));

    __half2 sA[4] = {h2z, h2z, h2z, h2z};
    __half2 sB[4] = {h2z, h2z, h2z, h2z};
    #pragma unroll
    for (int i = 0; i < 16; ++i) {
      uint4 wv = *(const uint4*)&Hp[(c0 + i)*96 + kp];
      __half2 h0, h1, h2c, h3;
      *(unsigned int*)&h0 = wv.x; *(unsigned int*)&h1 = wv.y;
      *(unsigned int*)&h2c = wv.z; *(unsigned int*)&h3 = wv.w;
      sA[0] = __hfma2(qpA[i], h0, sA[0]); sA[1] = __hfma2(qpA[i], h1, sA[1]);
      sA[2] = __hfma2(qpA[i], h2c, sA[2]); sA[3] = __hfma2(qpA[i], h3, sA[3]);
      sB[0] = __hfma2(qpB[i], h0, sB[0]); sB[1] = __hfma2(qpB[i], h1, sB[1]);
      sB[2] = __hfma2(qpB[i], h2c, sB[2]); sB[3] = __hfma2(qpB[i], h3, sB[3]);
    }
    #pragma unroll
    for (int jj = 0; jj < 4; ++jj) { sA[jj] = h2_comb(sA[jj]); sB[jj] = h2_comb(sB[jj]); }

    __half2 pA[4], pB[4];
    #pragma unroll
    for (int jj = 0; jj < 4; ++jj) {
      float2 fa = __half22float2(sA[jj]);
      float2 fb = __half22float2(sB[jj]);
      float pa0 = __builtin_exp2f(fa.x), pa1 = __builtin_exp2f(fa.y);
      float pb0 = __builtin_exp2f(fb.x), pb1 = __builtin_exp2f(fb.y);
      lA += pa0 + pa1; lB += pb0 + pb1;
      pA[jj] = __floats2half2_rn(pa0, pa1);
      pB[jj] = __floats2half2_rn(pb0, pb1);
    }

    #pragma unroll
    for (int i = 0; i < 16; ++i) {
      uint4 wv = *(const uint4*)&Hp[(c0 + i)*96 + kp];
      __half2 h0, h1, h2c, h3;
      *(unsigned int*)&h0 = wv.x; *(unsigned int*)&h1 = wv.y;
      *(unsigned int*)&h2c = wv.z; *(unsigned int*)&h3 = wv.w;
      __half2 ga = gpA[i];
      ga = __hfma2(pA[0], h0, ga); ga = __hfma2(pA[1], h1, ga);
      ga = __hfma2(pA[2], h2c, ga); ga = __hfma2(pA[3], h3, ga);
      gpA[i] = ga;
      __half2 gb = gpB[i];
      gb = __hfma2(pB[0], h0, gb); gb = __hfma2(pB[1], h1, gb);
      gb = __hfma2(pB[2], h2c, gb); gb = __hfma2(pB[3], h3, gb);
      gpB[i] = gb;
    }
  }

  // finalize g in fp32
  float gA[16], gB[16];
  {
    float rlA = 1.f / lA, rlB = 1.f / lB;
    #pragma unroll
    for (int i = 0; i < 16; ++i) {
      float2 fa = __half22float2(gpA[i]);
      float2 fb = __half22float2(gpB[i]);
      gA[i] = (fa.x + fa.y) * rlA;
      gB[i] = (fb.x + fb.y) * rlB;
    }
  }

  // park g (fp32 slots; packed h is dead from here on)
  __syncthreads();   // all attention reads complete before overwrite
  #pragma unroll
  for (int i = 0; i < 16; ++i) {
    Hs[(c0 + i)*192 + p0] = gA[i];
    Hs[(c0 + i)*192 + p1] = gB[i];
  }
  __syncthreads();

  // p[o] = bpv[o] + sum_c Cpvx[c][o]*g[c]  (own 16 outputs, all 64 c; reuse qt regs)
  #pragma unroll
  for (int i = 0; i < 16; ++i) { qtA[i] = bpv[c0 + i]; qtB[i] = qtA[i]; }
  for (int gq = 0; gq < 4; ++gq) {
    const int rg  = gq << 3;
    const int s0i = (t0 & ~31) | ((t0 & 31) ^ rg);
    const int s1i = (t1 & ~31) | ((t1 & 31) ^ rg);
    for (int c = gq*16; c < gq*16 + 16; ++c) {
      float ga = Hs[c*192 + s0i];
      float gb = Hs[c*192 + s1i];
      const float* cp = Cpv + c*64 + c0;
      #pragma unroll
      for (int i = 0; i < 16; ++i) {
        qtA[i] = fmaf(cp[i], ga, qtA[i]);
        qtB[i] = fmaf(cp[i], gb, qtB[i]);
      }
    }
  }
  __syncthreads();   // all g reads complete before overwrite

  // residual: res[c][t] = conv1(c,t) (recomputed) + p[c]
  {
    float hv[9];
    make_hv(t0, hv);
    #pragma unroll
    for (int i = 0; i < 16; ++i) {
      int c = c0 + i;
      float acc = chb[c];
      #pragma unroll
      for (int q = 0; q < 9; ++q) acc = fmaf(chw[c*9+q], hv[q], acc);
      Hs[c*192 + p0] = acc + qtA[i];
    }
    make_hv(t1, hv);
    #pragma unroll
    for (int i = 0; i < 16; ++i) {
      int c = c0 + i;
      float acc = chb[c];
      #pragma unroll
      for (int q = 0; q < 9; ++q) acc = fmaf(chw[c*9+q], hv[q], acc);
      Hs[c*192 + p1] = acc + qtB[i];
    }
  }
  __syncthreads();

  // conv2 (64->8): partial over own 16 input channels, combined across quarters
  // (xor8 DPP + xor16). Window offsets/masks hoisted out of the channel loop.
  float acc2A[8], acc2B[8];
  #pragma unroll
  for (int o = 0; o < 8; ++o) {
    acc2A[o] = (qg == 0) ? ch2b[o] : 0.f;
    acc2B[o] = (qg == 0) ? ch2b[o] : 0.f;
  }
  {
    int offA[9], offB[9];
    bool okA[9], okB[9];
    {
      const int y0 = t0 >> 6, xx0 = t0 & 63;
      const int y1 = t1 >> 6, xx1 = t1 & 63;
      #pragma unroll
      for (int dy = 0; dy < 3; ++dy) {
        #pragma unroll
        for (int dx = 0; dx < 3; ++dx) {
          int r0 = y0 + dy - 1, cc0 = xx0 + dx - 1;
          bool v0 = (r0 >= 0) && (r0 < 3) && (cc0 >= 0) && (cc0 < 64);
          int tok0 = r0*64 + cc0;
          okA[dy*3+dx] = v0;
          offA[dy*3+dx] = v0 ? ((tok0 & ~31) | ((tok0 & 31) ^ rot)) : p0;
          int r1 = y1 + dy - 1, cc1 = xx1 + dx - 1;
          bool v1 = (r1 >= 0) && (r1 < 3) && (cc1 >= 0) && (cc1 < 64);
          int tok1 = r1*64 + cc1;
          okB[dy*3+dx] = v1;
          offB[dy*3+dx] = v1 ? ((tok1 & ~31) | ((tok1 & 31) ^ rot)) : p1;
        }
      }
    }
    for (int i = 0; i < 16; ++i) {
      int c = c0 + i;
      const int cb = c*192;
      float win[9];
      #pragma unroll
      for (int q = 0; q < 9; ++q) win[q] = okA[q] ? Hs[cb + offA[q]] : 0.f;
      #pragma unroll
      for (int o = 0; o < 8; ++o) {
        const float* wrow = ch2w + o*576 + c*9;
        float a = acc2A[o];
        #pragma unroll
        for (int q = 0; q < 9; ++q) a = fmaf(wrow[q], win[q], a);
        acc2A[o] = a;
      }
      #pragma unroll
      for (int q = 0; q < 9; ++q) win[q] = okB[q] ? Hs[cb + offB[q]] : 0.f;
      #pragma unroll
      for (int o = 0; o < 8; ++o) {
        const float* wrow = ch2w + o*576 + c*9;
        float a = acc2B[o];
        #pragma unroll
        for (int q = 0; q < 9; ++q) a = fmaf(wrow[q], win[q], a);
        acc2B[o] = a;
      }
    }
  }
  #pragma unroll
  for (int o = 0; o < 8; ++o) {
    union { float f; int i; } ua; ua.f = acc2A[o];
    union { int i; float f; } ra; ra.i = xor8_dpp_i(ua.i);
    acc2A[o] += ra.f; acc2A[o] += __shfl_xor(acc2A[o], 16);
    union { float f; int i; } ub; ub.f = acc2B[o];
    union { int i; float f; } rb; rb.i = xor8_dpp_i(ub.i);
    acc2B[o] += rb.f; acc2B[o] += __shfl_xor(acc2B[o], 16);
  }
  if (qg == 0) {
    #pragma unroll
    for (int o = 0; o < 8; ++o) {
      c2out[b*1536 + o*192 + t0] = acc2A[o];
      c2out[b*1536 + o*192 + t1] = acc2B[o];
    }
  }
}

// ---------------- K2: fc1 GEMM  z1[4096][768] = relu(c2[4096][1536] @ w2^T + b2) ----------------
__launch_bounds__(256, 4)
__global__ void k2_fc1(const float* __restrict__ A, const float* __restrict__ w2,
                       const float* __restrict__ b2, float* __restrict__ z1) {
  __shared__ float As[128 * 33];
  __shared__ float Bs[32 * 68];
  const int tid = threadIdx.x;
  const int m0 = blockIdx.x * 128;
  const int n0 = blockIdx.y * 64;
  const int tm = tid & 15, tn = tid >> 4;   // tn 0..15

  float acc[8][4];
  #pragma unroll
  for (int i = 0; i < 8; ++i)
    #pragma unroll
    for (int j = 0; j < 4; ++j) acc[i][j] = 0.f;

  for (int k0 = 0; k0 < 1536; k0 += 32) {
    #pragma unroll
    for (int i = 0; i < 4; ++i) {   // stage A 128x32
      int j = tid + i*256;
      int mm = j >> 3, k4 = (j & 7) << 2;
      float4 v = *(const float4*)&A[(m0+mm)*1536 + k0 + k4];
      As[mm*33 + k4+0] = v.x; As[mm*33 + k4+1] = v.y;
      As[mm*33 + k4+2] = v.z; As[mm*33 + k4+3] = v.w;
    }
    #pragma unroll
    for (int i = 0; i < 2; ++i) {   // stage B 64x32 transposed -> Bs[k][68]
      int j = tid + i*256;
      int nn = j >> 3, k4 = (j & 7) << 2;
      float4 v = *(const float4*)&w2[(n0+nn)*1536 + k0 + k4];
      Bs[(k4+0)*68 + nn] = v.x; Bs[(k4+1)*68 + nn] = v.y;
      Bs[(k4+2)*68 + nn] = v.z; Bs[(k4+3)*68 + nn] = v.w;
    }
    __syncthreads();
    #pragma unroll
    for (int k = 0; k < 32; ++k) {
      float a[8];
      #pragma unroll
      for (int i = 0; i < 8; ++i) a[i] = As[(tm + 16*i)*33 + k];
      float4 bv = *(const float4*)&Bs[k*68 + tn*4];
      #pragma unroll
      for (int i = 0; i < 8; ++i) {
        acc[i][0] = fmaf(a[i], bv.x, acc[i][0]);
        acc[i][1] = fmaf(a[i], bv.y, acc[i][1]);
        acc[i][2] = fmaf(a[i], bv.z, acc[i][2]);
        acc[i][3] = fmaf(a[i], bv.w, acc[i][3]);
      }
    }
    __syncthreads();
  }
  float4 bb = *(const float4*)&b2[n0 + tn*4];
  #pragma unroll
  for (int i = 0; i < 8; ++i) {
    float4 r;
    r.x = fmaxf(acc[i][0] + bb.x, 0.f);
    r.y = fmaxf(acc[i][1] + bb.y, 0.f);
    r.z = fmaxf(acc[i][2] + bb.z, 0.f);
    r.w = fmaxf(acc[i][3] + bb.w, 0.f);
    *(float4*)&z1[(m0 + tm + 16*i)*768 + n0 + tn*4] = r;
  }
}

// ---------------- K3: fc2+relu+fc3 ----------------
__launch_bounds__(256, 2)
__global__ void k3_fc23(const float* __restrict__ z1, const float* __restrict__ w3,
                        const float* __restrict__ b3, const float* __restrict__ w4,
                        const float* __restrict__ b4, float* __restrict__ out) {
  __shared__ float Zs[16 * 772];
  __shared__ float Ws[32 * 68];
  __shared__ float red[256];
  const int tid = threadIdx.x;
  const int m0 = blockIdx.x * 16;
  const int tm = tid & 15, tn = tid >> 4;   // tn 0..15 -> 4 fc2 outputs each

  #pragma unroll
  for (int i = 0; i < 12; ++i) {   // stage Zs 16x768
    int j = tid + i*256;
    int mm = j / 192;
    int kq = j - mm*192;
    float4 v = *(const float4*)&z1[(m0+mm)*768 + kq*4];
    *(float4*)&Zs[mm*772 + kq*4] = v;
  }

  float a0 = 0.f, a1 = 0.f, a2 = 0.f, a3 = 0.f;
  for (int k0 = 0; k0 < 768; k0 += 32) {
    __syncthreads();
    #pragma unroll
    for (int i = 0; i < 2; ++i) {  // stage Ws[32k][68] transposed from w3[n][k]
      int j = tid + i*256;
      int nn = j >> 3, k4 = (j & 7) << 2;
      float4 v = *(const float4*)&w3[nn*768 + k0 + k4];
      Ws[(k4+0)*68 + nn] = v.x; Ws[(k4+1)*68 + nn] = v.y;
      Ws[(k4+2)*68 + nn] = v.z; Ws[(k4+3)*68 + nn] = v.w;
    }
    __syncthreads();
    #pragma unroll
    for (int k = 0; k < 32; k += 4) {
      float4 z  = *(const float4*)&Zs[tm*772 + k0 + k];
      float4 w0 = *(const float4*)&Ws[(k+0)*68 + tn*4];
      float4 w1v= *(const float4*)&Ws[(k+1)*68 + tn*4];
      float4 w2v= *(const float4*)&Ws[(k+2)*68 + tn*4];
      float4 w3v= *(const float4*)&Ws[(k+3)*68 + tn*4];
      a0 = fmaf(z.x, w0.x, a0); a1 = fmaf(z.x, w0.y, a1); a2 = fmaf(z.x, w0.z, a2); a3 = fmaf(z.x, w0.w, a3);
      a0 = fmaf(z.y, w1v.x, a0); a1 = fmaf(z.y, w1v.y, a1); a2 = fmaf(z.y, w1v.z, a2); a3 = fmaf(z.y, w1v.w, a3);
      a0 = fmaf(z.z, w2v.x, a0); a1 = fmaf(z.z, w2v.y, a1); a2 = fmaf(z.z, w2v.z, a2); a3 = fmaf(z.z, w2v.w, a3);
      a0 = fmaf(z.w, w3v.x, a0); a1 = fmaf(z.w, w3v.y, a1); a2 = fmaf(z.w, w3v.z, a2); a3 = fmaf(z.w, w3v.w, a3);
    }
  }
  float4 b3v = *(const float4*)&b3[tn*4];
  float4 w4v = *(const float4*)&w4[tn*4];
  float p = fmaxf(a0 + b3v.x, 0.f) * w4v.x
          + fmaxf(a1 + b3v.y, 0.f) * w4v.y
          + fmaxf(a2 + b3v.z, 0.f) * w4v.z
          + fmaxf(a3 + b3v.w, 0.f) * w4v.w;
  red[tid] = p;
  __syncthreads();
  if (tid < 16) {
    float s = 0.f;
    #pragma unroll
    for (int i = 0; i < 16; ++i) s += red[i*16 + tid];
    out[m0 + tid] = s + b4[0];
  }
}

extern "C" void kernel_launch(void* const* d_in, const int* in_sizes, int n_in,
                              void* d_out, int out_size, void* d_ws, size_t ws_size,
                              hipStream_t stream) {
  const float* x    = (const float*)d_in[0];
  const float* w1   = (const float*)d_in[1];
  const float* b1   = (const float*)d_in[2];
  const float* chw  = (const float*)d_in[3];
  const float* chb  = (const float*)d_in[4];
  const float* gnw  = (const float*)d_in[5];
  const float* gnb  = (const float*)d_in[6];
  const float* wq   = (const float*)d_in[7];
  const float* bq   = (const float*)d_in[8];
  const float* wk   = (const float*)d_in[9];
  const float* bk   = (const float*)d_in[10];
  const float* wv   = (const float*)d_in[11];
  const float* bv   = (const float*)d_in[12];
  const float* wp   = (const float*)d_in[13];
  const float* bp   = (const float*)d_in[14];
  const float* ch2w = (const float*)d_in[15];
  const float* ch2b = (const float*)d_in[16];
  const float* w2   = (const float*)d_in[17];
  const float* b2   = (const float*)d_in[18];
  const float* w3   = (const float*)d_in[19];
  const float* b3   = (const float*)d_in[20];
  const float* w4   = (const float*)d_in[21];
  const float* b4   = (const float*)d_in[22];
  (void)bk; (void)in_sizes; (void)n_in; (void)out_size; (void)ws_size;

  float* ws = (float*)d_ws;
  float* c2 = ws + WS_C2;
  float* z1 = ws + WS_Z1;
  float* out = (float*)d_out;

  hipLaunchKernelGGL(k0_precompute, dim3(34), dim3(256), 0, stream,
                     wq, bq, wk, bk, wv, bv, wp, bp, ws);
  hipLaunchKernelGGL(k1_sample, dim3(4096), dim3(384), 0, stream,
                     x, w1, b1, chw, chb, gnw, gnb, ch2w, ch2b, ws, c2);
  hipLaunchKernelGGL(k2_fc1, dim3(32, 12), dim3(256), 0, stream, c2, w2, b2, z1);
  hipLaunchKernelGGL(k3_fc23, dim3(256), dim3(256), 0, stream, z1, w3, b3, w4, b4, out);
}

// Round 15
// 2197.955 us; speedup vs baseline: 1.0071x; 1.0071x over previous
//
#include <hip/hip_runtime.h>
#include <hip/hip_fp16.h>

// ws layout (floats)
#define WS_GX   0                       // 4096: Gx[cp][c] = alpha*sum_o wk[o][c]*wq[o][cp]
#define WS_CPV  4096                    // 4096: Cpvx[c][o] = sum_m wp[o][m]*wv[m][c]
#define WS_QB   8192                    // 64:   alpha * Wk^T bq
#define WS_BPV  8256                    // 64:   Wp bv + bp
#define WS_C2   8448                    // 4096*1536 conv2 output (flattened fc input)
#define WS_Z1   (8448 + 4096*1536)      // 4096*768 fc1 output

// ---------------- K0: tiny precompute of fused weight products ----------------
__global__ void k0_precompute(const float* __restrict__ wq, const float* __restrict__ bq,
                              const float* __restrict__ wk, const float* __restrict__ bk,
                              const float* __restrict__ wv, const float* __restrict__ bv,
                              const float* __restrict__ wp, const float* __restrict__ bp,
                              float* __restrict__ ws) {
  int idx = blockIdx.x * 256 + threadIdx.x;
  const float ALPHA = 0.125f * 1.4426950408889634f;  // C^-0.5 * log2(e), folded into scores
  if (idx < 4096) {
    int cp = idx >> 6, c = idx & 63;
    float s = 0.f;
    for (int o = 0; o < 64; ++o) s += wk[o*64 + c] * wq[o*64 + cp];
    ws[WS_GX + idx] = s * ALPHA;
  } else if (idx < 8192) {
    int i = idx - 4096; int c = i >> 6, o = i & 63;
    float s = 0.f;
    for (int m = 0; m < 64; ++m) s += wp[o*64 + m] * wv[m*64 + c];
    ws[WS_CPV + i] = s;
  } else if (idx < 8256) {
    int c = idx - 8192;
    float s = 0.f;
    for (int o = 0; o < 64; ++o) s += wk[o*64 + c] * bq[o];
    ws[WS_QB + c] = s * ALPHA;
  } else if (idx < 8320) {
    int o = idx - 8256;
    float s = bp[o];
    for (int m = 0; m < 64; ++m) s += wp[o*64 + m] * bv[m];
    ws[WS_BPV + o] = s;
  }
}

// xor8 cross-lane add via DPP row_ror:8 — VALU pipe (verified r12).
__device__ __forceinline__ int xor8_dpp_i(int v) {
  return __builtin_amdgcn_update_dpp(0, v, 0x128, 0xF, 0xF, true);
}
__device__ __forceinline__ __half2 h2_comb(__half2 v) {
  int i0 = *(int*)&v;
  int r8 = xor8_dpp_i(i0);
  __half2 a = v; __half2 b; *(int*)&b = r8;
  __half2 s = __hadd2(a, b);
  int i1 = *(int*)&s;
  int r16 = __shfl_xor(i1, 16);
  __half2 c2; *(int*)&c2 = r16;
  return __hadd2(s, c2);
}

// fp32 Hs layout: slot = c*192 + (u&~31)|((u&31) ^ ROT(c>>4)), ROT(q)=q*8. Lane map r12:
// qg=(l>>3)&3 (bits 3,4), j = w*16+(l&7)+((l>>5)<<3). Verified r10-r12.
//
// r13/r14 A/B showed the pack-stage restructure changes NOTHING (identical conflicts
// 1.248e7 and ~1.9GB scratch traffic): the spill is structural to the attention loop's
// 64-reg persistent state (qp 32 + gp 32) at the (384,4) 64-VGPR tier. This is the
// measured session-best configuration (r13, 2199us); kept verbatim.
__launch_bounds__(384, 4)
__global__ void k1_sample(const float* __restrict__ x,
                          const float* __restrict__ w1, const float* __restrict__ b1,
                          const float* __restrict__ chw, const float* __restrict__ chb,
                          const float* __restrict__ gnw, const float* __restrict__ gnb,
                          const float* __restrict__ ch2w, const float* __restrict__ ch2b,
                          const float* __restrict__ ws, float* __restrict__ c2out) {
  __shared__ __align__(16) float Hs[64 * 192];
  __shared__ float redS[384];
  __shared__ float redQ[384];
  __shared__ float scS[64];
  __shared__ float shS[64];

  const int tt   = threadIdx.x;        // 0..383
  const int b    = blockIdx.x;         // sample
  const int w    = tt >> 6;            // wave 0..5
  const int l    = tt & 63;
  const int qg   = (l >> 3) & 3;       // channel quarter 0..3 (lane bits 3,4)
  const int c0   = qg << 4;            // channel base
  const int rot  = qg << 3;            // fp32 token rotation for own channels
  const int j    = w * 16 + (l & 7) + ((l >> 5) << 3);  // token-pair id 0..95
  const int t0   = j;                  // tokens owned by this thread
  const int t1   = j + 96;
  const int p0   = (t0 & ~31) | ((t0 & 31) ^ rot);
  const int p1   = (t1 & ~31) | ((t1 & 31) ^ rot);

  const float x0 = x[b*3+0], x1 = x[b*3+1], x2 = x[b*3+2];

  auto make_hv = [&](int t, float* hv) {
    int y = t >> 6, xx = t & 63;
    #pragma unroll
    for (int dy = 0; dy < 3; ++dy) {
      int r = y + dy - 1;
      bool rv = (r >= 0) && (r < 3);
      float xr = (r == 0) ? x0 : ((r == 1) ? x1 : x2);
      #pragma unroll
      for (int dx = 0; dx < 3; ++dx) {
        int cc = xx + dx - 1;
        bool cv = (cc >= 0) && (cc < 64);
        float w1v = cv ? w1[cc] : 0.f;
        float b1v = cv ? b1[cc] : 0.f;
        hv[dy*3+dx] = rv ? fmaf(xr, w1v, b1v) : 0.f;
      }
    }
  };

  // conv1 (1->64): own 16 channels at tokens t0, t1
  {
    float hv[9];
    make_hv(t0, hv);
    #pragma unroll
    for (int i = 0; i < 16; ++i) {
      int c = c0 + i;
      float acc = chb[c];
      #pragma unroll
      for (int q = 0; q < 9; ++q) acc = fmaf(chw[c*9+q], hv[q], acc);
      Hs[c*192 + p0] = acc;
    }
    make_hv(t1, hv);
    #pragma unroll
    for (int i = 0; i < 16; ++i) {
      int c = c0 + i;
      float acc = chb[c];
      #pragma unroll
      for (int q = 0; q < 9; ++q) acc = fmaf(chw[c*9+q], hv[q], acc);
      Hs[c*192 + p1] = acc;
    }
  }
  __syncthreads();

  // instance-norm stats
  {
    int c = tt & 63, seg = tt >> 6;
    int rc = (c >> 4) << 3;
    int base = c*192 + seg*32;
    float s = 0.f, q = 0.f;
    for (int u = 0; u < 32; ++u) {
      float v = Hs[base + (((u + c) & 31) ^ rc)];
      s += v; q = fmaf(v, v, q);
    }
    redS[tt] = s; redQ[tt] = q;
  }
  __syncthreads();
  if (tt < 64) {
    float s = 0.f, q = 0.f;
    #pragma unroll
    for (int i = 0; i < 6; ++i) { s += redS[i*64 + tt]; q += redQ[i*64 + tt]; }
    float mu  = s * (1.f/192.f);
    float var = q * (1.f/192.f) - mu*mu;
    float rs  = rsqrtf(var + 1e-5f);
    float sc  = gnw[tt] * rs;
    scS[tt] = sc;
    shS[tt] = gnb[tt] - mu * sc;
  }
  __syncthreads();
  // normalize in place (own 16 channels at t0, t1)
  #pragma unroll
  for (int i = 0; i < 16; ++i) {
    int c = c0 + i;
    float sc = scS[c], sh = shS[c];
    Hs[c*192 + p0] = fmaf(Hs[c*192 + p0], sc, sh);
    Hs[c*192 + p1] = fmaf(Hs[c*192 + p1], sc, sh);
  }
  __syncthreads();

  // ---- pack normalized h into half2, in place (first 24KB of Hs) ----
  // Thread tt packs channel c=tt&63, words seg*16..seg*16+15. Stage all 32 fp32 in
  // regs between barriers (packed region overlaps fp32 channels 0..31).
  unsigned int* Hp = (unsigned int*)Hs;
  {
    int c = tt & 63, seg = tt >> 6;
    int rc = (c >> 4) << 3;
    int sw = (c >> 4) << 2;
    float v[32];
    #pragma unroll
    for (int kk = 0; kk < 16; ++kk) {
      int k = seg*16 + kk;
      int tok = 2*k;
      int s0 = (tok & ~31) | ((tok & 31) ^ rc);   // token 2k (even; rc bit0=0 -> s1=s0+1)
      v[2*kk]   = Hs[c*192 + s0];
      v[2*kk+1] = Hs[c*192 + s0 + 1];
    }
    __syncthreads();
    #pragma unroll
    for (int kk = 0; kk < 16; ++kk) {
      int k = seg*16 + kk;
      int kp = (k & ~15) | ((k & 15) ^ sw);
      __half2 h2 = __floats2half2_rn(v[2*kk], v[2*kk+1]);
      Hp[c*96 + kp] = *(unsigned int*)&h2;
    }
  }
  __syncthreads();

  // ---- attention ----
  const float* __restrict__ Gx  = ws + WS_GX;
  const float* __restrict__ qb  = ws + WS_QB;
  const float* __restrict__ Cpv = ws + WS_CPV;
  const float* __restrict__ bpv = ws + WS_BPV;

  // q~ for own 16 channels, both tokens, reading packed h (fp32 accumulation).
  float qtA[16], qtB[16];
  #pragma unroll
  for (int i = 0; i < 16; ++i) { qtA[i] = qb[c0 + i]; qtB[i] = qtA[i]; }
  {
    const int k0A = t0 >> 1;          // t1>>1 = k0A + 48 (48 % 16 == 0 -> same swizzle class)
    const bool hiA = (t0 & 1) != 0;   // t1 has same parity as t0
    for (int gq = 0; gq < 4; ++gq) {
      int kA = (k0A & ~15) | ((k0A & 15) ^ (gq << 2));
      int kB = kA + 48;
      for (int cp = gq*16; cp < gq*16 + 16; ++cp) {
        unsigned int wA = Hp[cp*96 + kA];
        unsigned int wB = Hp[cp*96 + kB];
        __half2 a2; *(unsigned int*)&a2 = wA;
        __half2 b2; *(unsigned int*)&b2 = wB;
        float hA = hiA ? __high2float(a2) : __low2float(a2);
        float hB = hiA ? __high2float(b2) : __low2float(b2);
        const float* gx = Gx + cp*64 + c0;
        #pragma unroll
        for (int i = 0; i < 16; ++i) {
          qtA[i] = fmaf(gx[i], hA, qtA[i]);
          qtB[i] = fmaf(gx[i], hB, qtB[i]);
        }
      }
    }
  }

  // pack q~ into (q,q) half2 for hfma2
  __half2 qpA[16], qpB[16];
  #pragma unroll
  for (int i = 0; i < 16; ++i) {
    qpA[i] = __floats2half2_rn(qtA[i], qtA[i]);
    qpB[i] = __floats2half2_rn(qtB[i], qtB[i]);
  }

  // no-max softmax (|s| << 1, r11-verified) + g = attn @ h, all in packed half2.
  // Per step of 8 tokens: 16 b128 score reads + 16 b128 PV re-reads (vs 64 in fp32).
  const __half2 h2z = __floats2half2_rn(0.f, 0.f);
  __half2 gpA[16], gpB[16];
  #pragma unroll
  for (int i = 0; i < 16; ++i) { gpA[i] = h2z; gpB[i] = h2z; }
  float lA = 0.f, lB = 0.f;
  for (int u0 = 0; u0 < 192; u0 += 8) {
    const int k  = u0 >> 1;                          // 4-aligned
    const int kp = (k & ~15) | ((k & 15) ^ (qg << 2));

    __half2 sA[4] = {h2z, h2z, h2z, h2z};
    __half2 sB[4] = {h2z, h2z, h2z, h2z};
    #pragma unroll
    for (int i = 0; i < 16; ++i) {
      uint4 wv = *(const uint4*)&Hp[(c0 + i)*96 + kp];
      __half2 h0, h1, h2c, h3;
      *(unsigned int*)&h0 = wv.x; *(unsigned int*)&h1 = wv.y;
      *(unsigned int*)&h2c = wv.z; *(unsigned int*)&h3 = wv.w;
      sA[0] = __hfma2(qpA[i], h0, sA[0]); sA[1] = __hfma2(qpA[i], h1, sA[1]);
      sA[2] = __hfma2(qpA[i], h2c, sA[2]); sA[3] = __hfma2(qpA[i], h3, sA[3]);
      sB[0] = __hfma2(qpB[i], h0, sB[0]); sB[1] = __hfma2(qpB[i], h1, sB[1]);
      sB[2] = __hfma2(qpB[i], h2c, sB[2]); sB[3] = __hfma2(qpB[i], h3, sB[3]);
    }
    #pragma unroll
    for (int jj = 0; jj < 4; ++jj) { sA[jj] = h2_comb(sA[jj]); sB[jj] = h2_comb(sB[jj]); }

    // exp in fp32, denominators fp32, repack p as half2 pairs
    __half2 pA[4], pB[4];
    #pragma unroll
    for (int jj = 0; jj < 4; ++jj) {
      float2 fa = __half22float2(sA[jj]);
      float2 fb = __half22float2(sB[jj]);
      float pa0 = __builtin_exp2f(fa.x), pa1 = __builtin_exp2f(fa.y);
      float pb0 = __builtin_exp2f(fb.x), pb1 = __builtin_exp2f(fb.y);
      lA += pa0 + pa1; lB += pb0 + pb1;
      pA[jj] = __floats2half2_rn(pa0, pa1);
      pB[jj] = __floats2half2_rn(pb0, pb1);
    }

    #pragma unroll
    for (int i = 0; i < 16; ++i) {
      uint4 wv = *(const uint4*)&Hp[(c0 + i)*96 + kp];
      __half2 h0, h1, h2c, h3;
      *(unsigned int*)&h0 = wv.x; *(unsigned int*)&h1 = wv.y;
      *(unsigned int*)&h2c = wv.z; *(unsigned int*)&h3 = wv.w;
      __half2 ga = gpA[i];
      ga = __hfma2(pA[0], h0, ga); ga = __hfma2(pA[1], h1, ga);
      ga = __hfma2(pA[2], h2c, ga); ga = __hfma2(pA[3], h3, ga);
      gpA[i] = ga;
      __half2 gb = gpB[i];
      gb = __hfma2(pB[0], h0, gb); gb = __hfma2(pB[1], h1, gb);
      gb = __hfma2(pB[2], h2c, gb); gb = __hfma2(pB[3], h3, gb);
      gpB[i] = gb;
    }
  }

  // finalize g in fp32
  float gA[16], gB[16];
  {
    float rlA = 1.f / lA, rlB = 1.f / lB;
    #pragma unroll
    for (int i = 0; i < 16; ++i) {
      float2 fa = __half22float2(gpA[i]);
      float2 fb = __half22float2(gpB[i]);
      gA[i] = (fa.x + fa.y) * rlA;
      gB[i] = (fb.x + fb.y) * rlB;
    }
  }

  // park g (fp32 slots; packed h is dead from here on)
  __syncthreads();   // all attention reads complete before overwrite
  #pragma unroll
  for (int i = 0; i < 16; ++i) {
    Hs[(c0 + i)*192 + p0] = gA[i];
    Hs[(c0 + i)*192 + p1] = gB[i];
  }
  __syncthreads();

  // p[o] = bpv[o] + sum_c Cpvx[c][o]*g[c]  (own 16 outputs, all 64 c; reuse qt regs)
  #pragma unroll
  for (int i = 0; i < 16; ++i) { qtA[i] = bpv[c0 + i]; qtB[i] = qtA[i]; }
  for (int gq = 0; gq < 4; ++gq) {
    const int rg  = gq << 3;
    const int s0i = (t0 & ~31) | ((t0 & 31) ^ rg);
    const int s1i = (t1 & ~31) | ((t1 & 31) ^ rg);
    for (int c = gq*16; c < gq*16 + 16; ++c) {
      float ga = Hs[c*192 + s0i];
      float gb = Hs[c*192 + s1i];
      const float* cp = Cpv + c*64 + c0;
      #pragma unroll
      for (int i = 0; i < 16; ++i) {
        qtA[i] = fmaf(cp[i], ga, qtA[i]);
        qtB[i] = fmaf(cp[i], gb, qtB[i]);
      }
    }
  }
  __syncthreads();   // all g reads complete before overwrite

  // residual: res[c][t] = conv1(c,t) (recomputed) + p[c]
  {
    float hv[9];
    make_hv(t0, hv);
    #pragma unroll
    for (int i = 0; i < 16; ++i) {
      int c = c0 + i;
      float acc = chb[c];
      #pragma unroll
      for (int q = 0; q < 9; ++q) acc = fmaf(chw[c*9+q], hv[q], acc);
      Hs[c*192 + p0] = acc + qtA[i];
    }
    make_hv(t1, hv);
    #pragma unroll
    for (int i = 0; i < 16; ++i) {
      int c = c0 + i;
      float acc = chb[c];
      #pragma unroll
      for (int q = 0; q < 9; ++q) acc = fmaf(chw[c*9+q], hv[q], acc);
      Hs[c*192 + p1] = acc + qtB[i];
    }
  }
  __syncthreads();

  // conv2 (64->8): partial over own 16 input channels, combined across quarters
  // (xor8 DPP + xor16). Window offsets/masks hoisted out of the channel loop.
  float acc2A[8], acc2B[8];
  #pragma unroll
  for (int o = 0; o < 8; ++o) {
    acc2A[o] = (qg == 0) ? ch2b[o] : 0.f;
    acc2B[o] = (qg == 0) ? ch2b[o] : 0.f;
  }
  {
    int offA[9], offB[9];
    bool okA[9], okB[9];
    {
      const int y0 = t0 >> 6, xx0 = t0 & 63;
      const int y1 = t1 >> 6, xx1 = t1 & 63;
      #pragma unroll
      for (int dy = 0; dy < 3; ++dy) {
        #pragma unroll
        for (int dx = 0; dx < 3; ++dx) {
          int r0 = y0 + dy - 1, cc0 = xx0 + dx - 1;
          bool v0 = (r0 >= 0) && (r0 < 3) && (cc0 >= 0) && (cc0 < 64);
          int tok0 = r0*64 + cc0;
          okA[dy*3+dx] = v0;
          offA[dy*3+dx] = v0 ? ((tok0 & ~31) | ((tok0 & 31) ^ rot)) : p0;
          int r1 = y1 + dy - 1, cc1 = xx1 + dx - 1;
          bool v1 = (r1 >= 0) && (r1 < 3) && (cc1 >= 0) && (cc1 < 64);
          int tok1 = r1*64 + cc1;
          okB[dy*3+dx] = v1;
          offB[dy*3+dx] = v1 ? ((tok1 & ~31) | ((tok1 & 31) ^ rot)) : p1;
        }
      }
    }
    for (int i = 0; i < 16; ++i) {
      int c = c0 + i;
      const int cb = c*192;
      float win[9];
      #pragma unroll
      for (int q = 0; q < 9; ++q) win[q] = okA[q] ? Hs[cb + offA[q]] : 0.f;
      #pragma unroll
      for (int o = 0; o < 8; ++o) {
        const float* wrow = ch2w + o*576 + c*9;
        float a = acc2A[o];
        #pragma unroll
        for (int q = 0; q < 9; ++q) a = fmaf(wrow[q], win[q], a);
        acc2A[o] = a;
      }
      #pragma unroll
      for (int q = 0; q < 9; ++q) win[q] = okB[q] ? Hs[cb + offB[q]] : 0.f;
      #pragma unroll
      for (int o = 0; o < 8; ++o) {
        const float* wrow = ch2w + o*576 + c*9;
        float a = acc2B[o];
        #pragma unroll
        for (int q = 0; q < 9; ++q) a = fmaf(wrow[q], win[q], a);
        acc2B[o] = a;
      }
    }
  }
  #pragma unroll
  for (int o = 0; o < 8; ++o) {
    union { float f; int i; } ua; ua.f = acc2A[o];
    union { int i; float f; } ra; ra.i = xor8_dpp_i(ua.i);
    acc2A[o] += ra.f; acc2A[o] += __shfl_xor(acc2A[o], 16);
    union { float f; int i; } ub; ub.f = acc2B[o];
    union { int i; float f; } rb; rb.i = xor8_dpp_i(ub.i);
    acc2B[o] += rb.f; acc2B[o] += __shfl_xor(acc2B[o], 16);
  }
  if (qg == 0) {
    #pragma unroll
    for (int o = 0; o < 8; ++o) {
      c2out[b*1536 + o*192 + t0] = acc2A[o];
      c2out[b*1536 + o*192 + t1] = acc2B[o];
    }
  }
}

// ---------------- K2: fc1 GEMM  z1[4096][768] = relu(c2[4096][1536] @ w2^T + b2) ----------------
__launch_bounds__(256, 4)
__global__ void k2_fc1(const float* __restrict__ A, const float* __restrict__ w2,
                       const float* __restrict__ b2, float* __restrict__ z1) {
  __shared__ float As[128 * 33];
  __shared__ float Bs[32 * 68];
  const int tid = threadIdx.x;
  const int m0 = blockIdx.x * 128;
  const int n0 = blockIdx.y * 64;
  const int tm = tid & 15, tn = tid >> 4;   // tn 0..15

  float acc[8][4];
  #pragma unroll
  for (int i = 0; i < 8; ++i)
    #pragma unroll
    for (int j = 0; j < 4; ++j) acc[i][j] = 0.f;

  for (int k0 = 0; k0 < 1536; k0 += 32) {
    #pragma unroll
    for (int i = 0; i < 4; ++i) {   // stage A 128x32
      int j = tid + i*256;
      int mm = j >> 3, k4 = (j & 7) << 2;
      float4 v = *(const float4*)&A[(m0+mm)*1536 + k0 + k4];
      As[mm*33 + k4+0] = v.x; As[mm*33 + k4+1] = v.y;
      As[mm*33 + k4+2] = v.z; As[mm*33 + k4+3] = v.w;
    }
    #pragma unroll
    for (int i = 0; i < 2; ++i) {   // stage B 64x32 transposed -> Bs[k][68]
      int j = tid + i*256;
      int nn = j >> 3, k4 = (j & 7) << 2;
      float4 v = *(const float4*)&w2[(n0+nn)*1536 + k0 + k4];
      Bs[(k4+0)*68 + nn] = v.x; Bs[(k4+1)*68 + nn] = v.y;
      Bs[(k4+2)*68 + nn] = v.z; Bs[(k4+3)*68 + nn] = v.w;
    }
    __syncthreads();
    #pragma unroll
    for (int k = 0; k < 32; ++k) {
      float a[8];
      #pragma unroll
      for (int i = 0; i < 8; ++i) a[i] = As[(tm + 16*i)*33 + k];
      float4 bv = *(const float4*)&Bs[k*68 + tn*4];
      #pragma unroll
      for (int i = 0; i < 8; ++i) {
        acc[i][0] = fmaf(a[i], bv.x, acc[i][0]);
        acc[i][1] = fmaf(a[i], bv.y, acc[i][1]);
        acc[i][2] = fmaf(a[i], bv.z, acc[i][2]);
        acc[i][3] = fmaf(a[i], bv.w, acc[i][3]);
      }
    }
    __syncthreads();
  }
  float4 bb = *(const float4*)&b2[n0 + tn*4];
  #pragma unroll
  for (int i = 0; i < 8; ++i) {
    float4 r;
    r.x = fmaxf(acc[i][0] + bb.x, 0.f);
    r.y = fmaxf(acc[i][1] + bb.y, 0.f);
    r.z = fmaxf(acc[i][2] + bb.z, 0.f);
    r.w = fmaxf(acc[i][3] + bb.w, 0.f);
    *(float4*)&z1[(m0 + tm + 16*i)*768 + n0 + tn*4] = r;
  }
}

// ---------------- K3: fc2+relu+fc3 ----------------
__launch_bounds__(256, 2)
__global__ void k3_fc23(const float* __restrict__ z1, const float* __restrict__ w3,
                        const float* __restrict__ b3, const float* __restrict__ w4,
                        const float* __restrict__ b4, float* __restrict__ out) {
  __shared__ float Zs[16 * 772];
  __shared__ float Ws[32 * 68];
  __shared__ float red[256];
  const int tid = threadIdx.x;
  const int m0 = blockIdx.x * 16;
  const int tm = tid & 15, tn = tid >> 4;   // tn 0..15 -> 4 fc2 outputs each

  #pragma unroll
  for (int i = 0; i < 12; ++i) {   // stage Zs 16x768
    int j = tid + i*256;
    int mm = j / 192;
    int kq = j - mm*192;
    float4 v = *(const float4*)&z1[(m0+mm)*768 + kq*4];
    *(float4*)&Zs[mm*772 + kq*4] = v;
  }

  float a0 = 0.f, a1 = 0.f, a2 = 0.f, a3 = 0.f;
  for (int k0 = 0; k0 < 768; k0 += 32) {
    __syncthreads();
    #pragma unroll
    for (int i = 0; i < 2; ++i) {  // stage Ws[32k][68] transposed from w3[n][k]
      int j = tid + i*256;
      int nn = j >> 3, k4 = (j & 7) << 2;
      float4 v = *(const float4*)&w3[nn*768 + k0 + k4];
      Ws[(k4+0)*68 + nn] = v.x; Ws[(k4+1)*68 + nn] = v.y;
      Ws[(k4+2)*68 + nn] = v.z; Ws[(k4+3)*68 + nn] = v.w;
    }
    __syncthreads();
    #pragma unroll
    for (int k = 0; k < 32; k += 4) {
      float4 z  = *(const float4*)&Zs[tm*772 + k0 + k];
      float4 w0 = *(const float4*)&Ws[(k+0)*68 + tn*4];
      float4 w1v= *(const float4*)&Ws[(k+1)*68 + tn*4];
      float4 w2v= *(const float4*)&Ws[(k+2)*68 + tn*4];
      float4 w3v= *(const float4*)&Ws[(k+3)*68 + tn*4];
      a0 = fmaf(z.x, w0.x, a0); a1 = fmaf(z.x, w0.y, a1); a2 = fmaf(z.x, w0.z, a2); a3 = fmaf(z.x, w0.w, a3);
      a0 = fmaf(z.y, w1v.x, a0); a1 = fmaf(z.y, w1v.y, a1); a2 = fmaf(z.y, w1v.z, a2); a3 = fmaf(z.y, w1v.w, a3);
      a0 = fmaf(z.z, w2v.x, a0); a1 = fmaf(z.z, w2v.y, a1); a2 = fmaf(z.z, w2v.z, a2); a3 = fmaf(z.z, w2v.w, a3);
      a0 = fmaf(z.w, w3v.x, a0); a1 = fmaf(z.w, w3v.y, a1); a2 = fmaf(z.w, w3v.z, a2); a3 = fmaf(z.w, w3v.w, a3);
    }
  }
  float4 b3v = *(const float4*)&b3[tn*4];
  float4 w4v = *(const float4*)&w4[tn*4];
  float p = fmaxf(a0 + b3v.x, 0.f) * w4v.x
          + fmaxf(a1 + b3v.y, 0.f) * w4v.y
          + fmaxf(a2 + b3v.z, 0.f) * w4v.z
          + fmaxf(a3 + b3v.w, 0.f) * w4v.w;
  red[tid] = p;
  __syncthreads();
  if (tid < 16) {
    float s = 0.f;
    #pragma unroll
    for (int i = 0; i < 16; ++i) s += red[i*16 + tid];
    out[m0 + tid] = s + b4[0];
  }
}

extern "C" void kernel_launch(void* const* d_in, const int* in_sizes, int n_in,
                              void* d_out, int out_size, void* d_ws, size_t ws_size,
                              hipStream_t stream) {
  const float* x    = (const float*)d_in[0];
  const float* w1   = (const float*)d_in[1];
  const float* b1   = (const float*)d_in[2];
  const float* chw  = (const float*)d_in[3];
  const float* chb  = (const float*)d_in[4];
  const float* gnw  = (const float*)d_in[5];
  const float* gnb  = (const float*)d_in[6];
  const float* wq   = (const float*)d_in[7];
  const float* bq   = (const float*)d_in[8];
  const float* wk   = (const float*)d_in[9];
  const float* bk   = (const float*)d_in[10];
  const float* wv   = (const float*)d_in[11];
  const float* bv   = (const float*)d_in[12];
  const float* wp   = (const float*)d_in[13];
  const float* bp   = (const float*)d_in[14];
  const float* ch2w = (const float*)d_in[15];
  const float* ch2b = (const float*)d_in[16];
  const float* w2   = (const float*)d_in[17];
  const float* b2   = (const float*)d_in[18];
  const float* w3   = (const float*)d_in[19];
  const float* b3   = (const float*)d_in[20];
  const float* w4   = (const float*)d_in[21];
  const float* b4   = (const float*)d_in[22];
  (void)bk; (void)in_sizes; (void)n_in; (void)out_size; (void)ws_size;

  float* ws = (float*)d_ws;
  float* c2 = ws + WS_C2;
  float* z1 = ws + WS_Z1;
  float* out = (float*)d_out;

  hipLaunchKernelGGL(k0_precompute, dim3(34), dim3(256), 0, stream,
                     wq, bq, wk, bk, wv, bv, wp, bp, ws);
  hipLaunchKernelGGL(k1_sample, dim3(4096), dim3(384), 0, stream,
                     x, w1, b1, chw, chb, gnw, gnb, ch2w, ch2b, ws, c2);
  hipLaunchKernelGGL(k2_fc1, dim3(32, 12), dim3(256), 0, stream, c2, w2, b2, z1);
  hipLaunchKernelGGL(k3_fc23, dim3(256), dim3(256), 0, stream, z1, w3, b3, w4, b4, out);
}

// Round 16
// 1753.824 us; speedup vs baseline: 1.2621x; 1.2532x over previous
//
#include <hip/hip_runtime.h>
#include <hip/hip_fp16.h>

// ws layout (floats)
#define WS_GX   0                       // 4096: Gx[cp][c] = alpha*sum_o wk[o][c]*wq[o][cp]
#define WS_CPV  4096                    // 4096: Cpvx[c][o] = sum_m wp[o][m]*wv[m][c]
#define WS_QB   8192                    // 64:   alpha * Wk^T bq
#define WS_BPV  8256                    // 64:   Wp bv + bp
#define WS_C2   8448                    // 4096*1536 conv2 output (flattened fc input)
#define WS_Z1   (8448 + 4096*1536)      // 4096*768 fc1 output

// ---------------- K0: tiny precompute of fused weight products ----------------
__global__ void k0_precompute(const float* __restrict__ wq, const float* __restrict__ bq,
                              const float* __restrict__ wk, const float* __restrict__ bk,
                              const float* __restrict__ wv, const float* __restrict__ bv,
                              const float* __restrict__ wp, const float* __restrict__ bp,
                              float* __restrict__ ws) {
  int idx = blockIdx.x * 256 + threadIdx.x;
  const float ALPHA = 0.125f * 1.4426950408889634f;  // C^-0.5 * log2(e), folded into scores
  if (idx < 4096) {
    int cp = idx >> 6, c = idx & 63;
    float s = 0.f;
    for (int o = 0; o < 64; ++o) s += wk[o*64 + c] * wq[o*64 + cp];
    ws[WS_GX + idx] = s * ALPHA;
  } else if (idx < 8192) {
    int i = idx - 4096; int c = i >> 6, o = i & 63;
    float s = 0.f;
    for (int m = 0; m < 64; ++m) s += wp[o*64 + m] * wv[m*64 + c];
    ws[WS_CPV + i] = s;
  } else if (idx < 8256) {
    int c = idx - 8192;
    float s = 0.f;
    for (int o = 0; o < 64; ++o) s += wk[o*64 + c] * bq[o];
    ws[WS_QB + c] = s * ALPHA;
  } else if (idx < 8320) {
    int o = idx - 8256;
    float s = bp[o];
    for (int m = 0; m < 64; ++m) s += wp[o*64 + m] * bv[m];
    ws[WS_BPV + o] = s;
  }
}

// xor8 cross-lane add via DPP row_ror:8 — VALU pipe (verified r12).
__device__ __forceinline__ int xor8_dpp_i(int v) {
  return __builtin_amdgcn_update_dpp(0, v, 0x128, 0xF, 0xF, true);
}
__device__ __forceinline__ __half2 h2_comb(__half2 v) {
  int i0 = *(int*)&v;
  int r8 = xor8_dpp_i(i0);
  __half2 a = v; __half2 b; *(int*)&b = r8;
  __half2 s = __hadd2(a, b);
  int i1 = *(int*)&s;
  int r16 = __shfl_xor(i1, 16);
  __half2 c2; *(int*)&c2 = r16;
  return __hadd2(s, c2);
}

// fp32 Hs layout: slot = c*192 + (u&~31)|((u&31) ^ ROT(c>>4)), ROT(q)=q*8. Lane map r12:
// qg=(l>>3)&3 (bits 3,4), j = w*16+(l&7)+((l>>5)<<3). Verified r10-r12.
//
// r16: TOKEN-PACKED half2 state. r13/r14 A/B proved the ~1.9GB scratch traffic is
// structural to the attention loop's 64-reg persistent state (qp 32 + gp 32 in the
// old (q,q)/(parity,parity) layout) at the (384,4) 64-VGPR tier. This version packs
// the TWO TOKENS into each half2 instead: qp[i]=(qA,qB), gp[i]=(gA,gB) -> persistent
// state 32 regs. MAC count unchanged (two hfma2 per h-word with lane-broadcast
// __low2half2/__high2half2 operands, which the backend folds into v_pk_fma op_sel);
// s[u] and p[u] become (A,B)-packed; epilogue loses the cross-parity add.
__launch_bounds__(384, 4)
__global__ void k1_sample(const float* __restrict__ x,
                          const float* __restrict__ w1, const float* __restrict__ b1,
                          const float* __restrict__ chw, const float* __restrict__ chb,
                          const float* __restrict__ gnw, const float* __restrict__ gnb,
                          const float* __restrict__ ch2w, const float* __restrict__ ch2b,
                          const float* __restrict__ ws, float* __restrict__ c2out) {
  __shared__ __align__(16) float Hs[64 * 192];
  __shared__ float redS[384];
  __shared__ float redQ[384];
  __shared__ float scS[64];
  __shared__ float shS[64];

  const int tt   = threadIdx.x;        // 0..383
  const int b    = blockIdx.x;         // sample
  const int w    = tt >> 6;            // wave 0..5
  const int l    = tt & 63;
  const int qg   = (l >> 3) & 3;       // channel quarter 0..3 (lane bits 3,4)
  const int c0   = qg << 4;            // channel base
  const int rot  = qg << 3;            // fp32 token rotation for own channels
  const int j    = w * 16 + (l & 7) + ((l >> 5) << 3);  // token-pair id 0..95
  const int t0   = j;                  // tokens owned by this thread
  const int t1   = j + 96;
  const int p0   = (t0 & ~31) | ((t0 & 31) ^ rot);
  const int p1   = (t1 & ~31) | ((t1 & 31) ^ rot);

  const float x0 = x[b*3+0], x1 = x[b*3+1], x2 = x[b*3+2];

  auto make_hv = [&](int t, float* hv) {
    int y = t >> 6, xx = t & 63;
    #pragma unroll
    for (int dy = 0; dy < 3; ++dy) {
      int r = y + dy - 1;
      bool rv = (r >= 0) && (r < 3);
      float xr = (r == 0) ? x0 : ((r == 1) ? x1 : x2);
      #pragma unroll
      for (int dx = 0; dx < 3; ++dx) {
        int cc = xx + dx - 1;
        bool cv = (cc >= 0) && (cc < 64);
        float w1v = cv ? w1[cc] : 0.f;
        float b1v = cv ? b1[cc] : 0.f;
        hv[dy*3+dx] = rv ? fmaf(xr, w1v, b1v) : 0.f;
      }
    }
  };

  // conv1 (1->64): own 16 channels at tokens t0, t1
  {
    float hv[9];
    make_hv(t0, hv);
    #pragma unroll
    for (int i = 0; i < 16; ++i) {
      int c = c0 + i;
      float acc = chb[c];
      #pragma unroll
      for (int q = 0; q < 9; ++q) acc = fmaf(chw[c*9+q], hv[q], acc);
      Hs[c*192 + p0] = acc;
    }
    make_hv(t1, hv);
    #pragma unroll
    for (int i = 0; i < 16; ++i) {
      int c = c0 + i;
      float acc = chb[c];
      #pragma unroll
      for (int q = 0; q < 9; ++q) acc = fmaf(chw[c*9+q], hv[q], acc);
      Hs[c*192 + p1] = acc;
    }
  }
  __syncthreads();

  // instance-norm stats
  {
    int c = tt & 63, seg = tt >> 6;
    int rc = (c >> 4) << 3;
    int base = c*192 + seg*32;
    float s = 0.f, q = 0.f;
    for (int u = 0; u < 32; ++u) {
      float v = Hs[base + (((u + c) & 31) ^ rc)];
      s += v; q = fmaf(v, v, q);
    }
    redS[tt] = s; redQ[tt] = q;
  }
  __syncthreads();
  if (tt < 64) {
    float s = 0.f, q = 0.f;
    #pragma unroll
    for (int i = 0; i < 6; ++i) { s += redS[i*64 + tt]; q += redQ[i*64 + tt]; }
    float mu  = s * (1.f/192.f);
    float var = q * (1.f/192.f) - mu*mu;
    float rs  = rsqrtf(var + 1e-5f);
    float sc  = gnw[tt] * rs;
    scS[tt] = sc;
    shS[tt] = gnb[tt] - mu * sc;
  }
  __syncthreads();
  // normalize in place (own 16 channels at t0, t1)
  #pragma unroll
  for (int i = 0; i < 16; ++i) {
    int c = c0 + i;
    float sc = scS[c], sh = shS[c];
    Hs[c*192 + p0] = fmaf(Hs[c*192 + p0], sc, sh);
    Hs[c*192 + p1] = fmaf(Hs[c*192 + p1], sc, sh);
  }
  __syncthreads();

  // ---- pack normalized h into half2, in place (first 24KB of Hs) ----
  unsigned int* Hp = (unsigned int*)Hs;
  {
    int c = tt & 63, seg = tt >> 6;
    int rc = (c >> 4) << 3;
    int sw = (c >> 4) << 2;
    float v[32];
    #pragma unroll
    for (int kk = 0; kk < 16; ++kk) {
      int k = seg*16 + kk;
      int tok = 2*k;
      int s0 = (tok & ~31) | ((tok & 31) ^ rc);   // token 2k (even; rc bit0=0 -> s1=s0+1)
      v[2*kk]   = Hs[c*192 + s0];
      v[2*kk+1] = Hs[c*192 + s0 + 1];
    }
    __syncthreads();
    #pragma unroll
    for (int kk = 0; kk < 16; ++kk) {
      int k = seg*16 + kk;
      int kp = (k & ~15) | ((k & 15) ^ sw);
      __half2 h2 = __floats2half2_rn(v[2*kk], v[2*kk+1]);
      Hp[c*96 + kp] = *(unsigned int*)&h2;
    }
  }
  __syncthreads();

  // ---- attention ----
  const float* __restrict__ Gx  = ws + WS_GX;
  const float* __restrict__ qb  = ws + WS_QB;
  const float* __restrict__ Cpv = ws + WS_CPV;
  const float* __restrict__ bpv = ws + WS_BPV;

  // q~ for own 16 channels, both tokens, reading packed h (fp32 accumulation).
  float qtA[16], qtB[16];
  #pragma unroll
  for (int i = 0; i < 16; ++i) { qtA[i] = qb[c0 + i]; qtB[i] = qtA[i]; }
  {
    const int k0A = t0 >> 1;          // t1>>1 = k0A + 48 (48 % 16 == 0 -> same swizzle class)
    const bool hiA = (t0 & 1) != 0;   // t1 has same parity as t0
    for (int gq = 0; gq < 4; ++gq) {
      int kA = (k0A & ~15) | ((k0A & 15) ^ (gq << 2));
      int kB = kA + 48;
      for (int cp = gq*16; cp < gq*16 + 16; ++cp) {
        unsigned int wA = Hp[cp*96 + kA];
        unsigned int wB = Hp[cp*96 + kB];
        __half2 a2; *(unsigned int*)&a2 = wA;
        __half2 b2; *(unsigned int*)&b2 = wB;
        float hA = hiA ? __high2float(a2) : __low2float(a2);
        float hB = hiA ? __high2float(b2) : __low2float(b2);
        const float* gx = Gx + cp*64 + c0;
        #pragma unroll
        for (int i = 0; i < 16; ++i) {
          qtA[i] = fmaf(gx[i], hA, qtA[i]);
          qtB[i] = fmaf(gx[i], hB, qtB[i]);
        }
      }
    }
  }

  // TOKEN-PACKED q: qp[i] = (qA, qB) — 16 persistent regs (was 32).
  __half2 qp[16];
  #pragma unroll
  for (int i = 0; i < 16; ++i) qp[i] = __floats2half2_rn(qtA[i], qtB[i]);

  // no-max softmax (|s| << 1, r11-verified) + g = attn @ h, token-packed half2.
  // s[u] = (sA_u, sB_u); per h-word two hfma2 with lane-broadcast (op_sel) operands.
  const __half2 h2z = __floats2half2_rn(0.f, 0.f);
  __half2 gp[16];                       // gp[i] = (gA_i, gB_i) — 16 persistent regs (was 32)
  #pragma unroll
  for (int i = 0; i < 16; ++i) gp[i] = h2z;
  float lA = 0.f, lB = 0.f;
  for (int u0 = 0; u0 < 192; u0 += 8) {
    const int k  = u0 >> 1;                          // 4-aligned
    const int kp = (k & ~15) | ((k & 15) ^ (qg << 2));

    __half2 s[8];
    #pragma unroll
    for (int u = 0; u < 8; ++u) s[u] = h2z;
    #pragma unroll
    for (int i = 0; i < 16; ++i) {
      uint4 wv = *(const uint4*)&Hp[(c0 + i)*96 + kp];
      __half2 h01, h23, h45, h67;
      *(unsigned int*)&h01 = wv.x; *(unsigned int*)&h23 = wv.y;
      *(unsigned int*)&h45 = wv.z; *(unsigned int*)&h67 = wv.w;
      __half2 q2 = qp[i];
      s[0] = __hfma2(q2, __low2half2(h01),  s[0]);
      s[1] = __hfma2(q2, __high2half2(h01), s[1]);
      s[2] = __hfma2(q2, __low2half2(h23),  s[2]);
      s[3] = __hfma2(q2, __high2half2(h23), s[3]);
      s[4] = __hfma2(q2, __low2half2(h45),  s[4]);
      s[5] = __hfma2(q2, __high2half2(h45), s[5]);
      s[6] = __hfma2(q2, __low2half2(h67),  s[6]);
      s[7] = __hfma2(q2, __high2half2(h67), s[7]);
    }
    #pragma unroll
    for (int u = 0; u < 8; ++u) s[u] = h2_comb(s[u]);

    // exp in fp32, denominators fp32, p[u] = (pA_u, pB_u)
    __half2 p[8];
    #pragma unroll
    for (int u = 0; u < 8; ++u) {
      float2 f = __half22float2(s[u]);
      float pa = __builtin_exp2f(f.x), pb = __builtin_exp2f(f.y);
      lA += pa; lB += pb;
      p[u] = __floats2half2_rn(pa, pb);
    }

    #pragma unroll
    for (int i = 0; i < 16; ++i) {
      uint4 wv = *(const uint4*)&Hp[(c0 + i)*96 + kp];
      __half2 h01, h23, h45, h67;
      *(unsigned int*)&h01 = wv.x; *(unsigned int*)&h23 = wv.y;
      *(unsigned int*)&h45 = wv.z; *(unsigned int*)&h67 = wv.w;
      __half2 g2 = gp[i];
      g2 = __hfma2(p[0], __low2half2(h01),  g2);
      g2 = __hfma2(p[1], __high2half2(h01), g2);
      g2 = __hfma2(p[2], __low2half2(h23),  g2);
      g2 = __hfma2(p[3], __high2half2(h23), g2);
      g2 = __hfma2(p[4], __low2half2(h45),  g2);
      g2 = __hfma2(p[5], __high2half2(h45), g2);
      g2 = __hfma2(p[6], __low2half2(h67),  g2);
      g2 = __hfma2(p[7], __high2half2(h67), g2);
      gp[i] = g2;
    }
  }

  // finalize g in fp32 (low half = token A, high = token B; no cross-parity add)
  float gA[16], gB[16];
  {
    float rlA = 1.f / lA, rlB = 1.f / lB;
    #pragma unroll
    for (int i = 0; i < 16; ++i) {
      float2 f = __half22float2(gp[i]);
      gA[i] = f.x * rlA;
      gB[i] = f.y * rlB;
    }
  }

  // park g (fp32 slots; packed h is dead from here on)
  __syncthreads();   // all attention reads complete before overwrite
  #pragma unroll
  for (int i = 0; i < 16; ++i) {
    Hs[(c0 + i)*192 + p0] = gA[i];
    Hs[(c0 + i)*192 + p1] = gB[i];
  }
  __syncthreads();

  // p[o] = bpv[o] + sum_c Cpvx[c][o]*g[c]  (own 16 outputs, all 64 c; reuse qt regs)
  #pragma unroll
  for (int i = 0; i < 16; ++i) { qtA[i] = bpv[c0 + i]; qtB[i] = qtA[i]; }
  for (int gq = 0; gq < 4; ++gq) {
    const int rg  = gq << 3;
    const int s0i = (t0 & ~31) | ((t0 & 31) ^ rg);
    const int s1i = (t1 & ~31) | ((t1 & 31) ^ rg);
    for (int c = gq*16; c < gq*16 + 16; ++c) {
      float ga = Hs[c*192 + s0i];
      float gb = Hs[c*192 + s1i];
      const float* cp = Cpv + c*64 + c0;
      #pragma unroll
      for (int i = 0; i < 16; ++i) {
        qtA[i] = fmaf(cp[i], ga, qtA[i]);
        qtB[i] = fmaf(cp[i], gb, qtB[i]);
      }
    }
  }
  __syncthreads();   // all g reads complete before overwrite

  // residual: res[c][t] = conv1(c,t) (recomputed) + p[c]
  {
    float hv[9];
    make_hv(t0, hv);
    #pragma unroll
    for (int i = 0; i < 16; ++i) {
      int c = c0 + i;
      float acc = chb[c];
      #pragma unroll
      for (int q = 0; q < 9; ++q) acc = fmaf(chw[c*9+q], hv[q], acc);
      Hs[c*192 + p0] = acc + qtA[i];
    }
    make_hv(t1, hv);
    #pragma unroll
    for (int i = 0; i < 16; ++i) {
      int c = c0 + i;
      float acc = chb[c];
      #pragma unroll
      for (int q = 0; q < 9; ++q) acc = fmaf(chw[c*9+q], hv[q], acc);
      Hs[c*192 + p1] = acc + qtB[i];
    }
  }
  __syncthreads();

  // conv2 (64->8): partial over own 16 input channels, combined across quarters
  // (xor8 DPP + xor16). Window offsets/masks hoisted out of the channel loop.
  float acc2A[8], acc2B[8];
  #pragma unroll
  for (int o = 0; o < 8; ++o) {
    acc2A[o] = (qg == 0) ? ch2b[o] : 0.f;
    acc2B[o] = (qg == 0) ? ch2b[o] : 0.f;
  }
  {
    int offA[9], offB[9];
    bool okA[9], okB[9];
    {
      const int y0 = t0 >> 6, xx0 = t0 & 63;
      const int y1 = t1 >> 6, xx1 = t1 & 63;
      #pragma unroll
      for (int dy = 0; dy < 3; ++dy) {
        #pragma unroll
        for (int dx = 0; dx < 3; ++dx) {
          int r0 = y0 + dy - 1, cc0 = xx0 + dx - 1;
          bool v0 = (r0 >= 0) && (r0 < 3) && (cc0 >= 0) && (cc0 < 64);
          int tok0 = r0*64 + cc0;
          okA[dy*3+dx] = v0;
          offA[dy*3+dx] = v0 ? ((tok0 & ~31) | ((tok0 & 31) ^ rot)) : p0;
          int r1 = y1 + dy - 1, cc1 = xx1 + dx - 1;
          bool v1 = (r1 >= 0) && (r1 < 3) && (cc1 >= 0) && (cc1 < 64);
          int tok1 = r1*64 + cc1;
          okB[dy*3+dx] = v1;
          offB[dy*3+dx] = v1 ? ((tok1 & ~31) | ((tok1 & 31) ^ rot)) : p1;
        }
      }
    }
    for (int i = 0; i < 16; ++i) {
      int c = c0 + i;
      const int cb = c*192;
      float win[9];
      #pragma unroll
      for (int q = 0; q < 9; ++q) win[q] = okA[q] ? Hs[cb + offA[q]] : 0.f;
      #pragma unroll
      for (int o = 0; o < 8; ++o) {
        const float* wrow = ch2w + o*576 + c*9;
        float a = acc2A[o];
        #pragma unroll
        for (int q = 0; q < 9; ++q) a = fmaf(wrow[q], win[q], a);
        acc2A[o] = a;
      }
      #pragma unroll
      for (int q = 0; q < 9; ++q) win[q] = okB[q] ? Hs[cb + offB[q]] : 0.f;
      #pragma unroll
      for (int o = 0; o < 8; ++o) {
        const float* wrow = ch2w + o*576 + c*9;
        float a = acc2B[o];
        #pragma unroll
        for (int q = 0; q < 9; ++q) a = fmaf(wrow[q], win[q], a);
        acc2B[o] = a;
      }
    }
  }
  #pragma unroll
  for (int o = 0; o < 8; ++o) {
    union { float f; int i; } ua; ua.f = acc2A[o];
    union { int i; float f; } ra; ra.i = xor8_dpp_i(ua.i);
    acc2A[o] += ra.f; acc2A[o] += __shfl_xor(acc2A[o], 16);
    union { float f; int i; } ub; ub.f = acc2B[o];
    union { int i; float f; } rb; rb.i = xor8_dpp_i(ub.i);
    acc2B[o] += rb.f; acc2B[o] += __shfl_xor(acc2B[o], 16);
  }
  if (qg == 0) {
    #pragma unroll
    for (int o = 0; o < 8; ++o) {
      c2out[b*1536 + o*192 + t0] = acc2A[o];
      c2out[b*1536 + o*192 + t1] = acc2B[o];
    }
  }
}

// ---------------- K2: fc1 GEMM  z1[4096][768] = relu(c2[4096][1536] @ w2^T + b2) ----------------
__launch_bounds__(256, 4)
__global__ void k2_fc1(const float* __restrict__ A, const float* __restrict__ w2,
                       const float* __restrict__ b2, float* __restrict__ z1) {
  __shared__ float As[128 * 33];
  __shared__ float Bs[32 * 68];
  const int tid = threadIdx.x;
  const int m0 = blockIdx.x * 128;
  const int n0 = blockIdx.y * 64;
  const int tm = tid & 15, tn = tid >> 4;   // tn 0..15

  float acc[8][4];
  #pragma unroll
  for (int i = 0; i < 8; ++i)
    #pragma unroll
    for (int j = 0; j < 4; ++j) acc[i][j] = 0.f;

  for (int k0 = 0; k0 < 1536; k0 += 32) {
    #pragma unroll
    for (int i = 0; i < 4; ++i) {   // stage A 128x32
      int j = tid + i*256;
      int mm = j >> 3, k4 = (j & 7) << 2;
      float4 v = *(const float4*)&A[(m0+mm)*1536 + k0 + k4];
      As[mm*33 + k4+0] = v.x; As[mm*33 + k4+1] = v.y;
      As[mm*33 + k4+2] = v.z; As[mm*33 + k4+3] = v.w;
    }
    #pragma unroll
    for (int i = 0; i < 2; ++i) {   // stage B 64x32 transposed -> Bs[k][68]
      int j = tid + i*256;
      int nn = j >> 3, k4 = (j & 7) << 2;
      float4 v = *(const float4*)&w2[(n0+nn)*1536 + k0 + k4];
      Bs[(k4+0)*68 + nn] = v.x; Bs[(k4+1)*68 + nn] = v.y;
      Bs[(k4+2)*68 + nn] = v.z; Bs[(k4+3)*68 + nn] = v.w;
    }
    __syncthreads();
    #pragma unroll
    for (int k = 0; k < 32; ++k) {
      float a[8];
      #pragma unroll
      for (int i = 0; i < 8; ++i) a[i] = As[(tm + 16*i)*33 + k];
      float4 bv = *(const float4*)&Bs[k*68 + tn*4];
      #pragma unroll
      for (int i = 0; i < 8; ++i) {
        acc[i][0] = fmaf(a[i], bv.x, acc[i][0]);
        acc[i][1] = fmaf(a[i], bv.y, acc[i][1]);
        acc[i][2] = fmaf(a[i], bv.z, acc[i][2]);
        acc[i][3] = fmaf(a[i], bv.w, acc[i][3]);
      }
    }
    __syncthreads();
  }
  float4 bb = *(const float4*)&b2[n0 + tn*4];
  #pragma unroll
  for (int i = 0; i < 8; ++i) {
    float4 r;
    r.x = fmaxf(acc[i][0] + bb.x, 0.f);
    r.y = fmaxf(acc[i][1] + bb.y, 0.f);
    r.z = fmaxf(acc[i][2] + bb.z, 0.f);
    r.w = fmaxf(acc[i][3] + bb.w, 0.f);
    *(float4*)&z1[(m0 + tm + 16*i)*768 + n0 + tn*4] = r;
  }
}

// ---------------- K3: fc2+relu+fc3 ----------------
__launch_bounds__(256, 2)
__global__ void k3_fc23(const float* __restrict__ z1, const float* __restrict__ w3,
                        const float* __restrict__ b3, const float* __restrict__ w4,
                        const float* __restrict__ b4, float* __restrict__ out) {
  __shared__ float Zs[16 * 772];
  __shared__ float Ws[32 * 68];
  __shared__ float red[256];
  const int tid = threadIdx.x;
  const int m0 = blockIdx.x * 16;
  const int tm = tid & 15, tn = tid >> 4;   // tn 0..15 -> 4 fc2 outputs each

  #pragma unroll
  for (int i = 0; i < 12; ++i) {   // stage Zs 16x768
    int j = tid + i*256;
    int mm = j / 192;
    int kq = j - mm*192;
    float4 v = *(const float4*)&z1[(m0+mm)*768 + kq*4];
    *(float4*)&Zs[mm*772 + kq*4] = v;
  }

  float a0 = 0.f, a1 = 0.f, a2 = 0.f, a3 = 0.f;
  for (int k0 = 0; k0 < 768; k0 += 32) {
    __syncthreads();
    #pragma unroll
    for (int i = 0; i < 2; ++i) {  // stage Ws[32k][68] transposed from w3[n][k]
      int j = tid + i*256;
      int nn = j >> 3, k4 = (j & 7) << 2;
      float4 v = *(const float4*)&w3[nn*768 + k0 + k4];
      Ws[(k4+0)*68 + nn] = v.x; Ws[(k4+1)*68 + nn] = v.y;
      Ws[(k4+2)*68 + nn] = v.z; Ws[(k4+3)*68 + nn] = v.w;
    }
    __syncthreads();
    #pragma unroll
    for (int k = 0; k < 32; k += 4) {
      float4 z  = *(const float4*)&Zs[tm*772 + k0 + k];
      float4 w0 = *(const float4*)&Ws[(k+0)*68 + tn*4];
      float4 w1v= *(const float4*)&Ws[(k+1)*68 + tn*4];
      float4 w2v= *(const float4*)&Ws[(k+2)*68 + tn*4];
      float4 w3v= *(const float4*)&Ws[(k+3)*68 + tn*4];
      a0 = fmaf(z.x, w0.x, a0); a1 = fmaf(z.x, w0.y, a1); a2 = fmaf(z.x, w0.z, a2); a3 = fmaf(z.x, w0.w, a3);
      a0 = fmaf(z.y, w1v.x, a0); a1 = fmaf(z.y, w1v.y, a1); a2 = fmaf(z.y, w1v.z, a2); a3 = fmaf(z.y, w1v.w, a3);
      a0 = fmaf(z.z, w2v.x, a0); a1 = fmaf(z.z, w2v.y, a1); a2 = fmaf(z.z, w2v.z, a2); a3 = fmaf(z.z, w2v.w, a3);
      a0 = fmaf(z.w, w3v.x, a0); a1 = fmaf(z.w, w3v.y, a1); a2 = fmaf(z.w, w3v.z, a2); a3 = fmaf(z.w, w3v.w, a3);
    }
  }
  float4 b3v = *(const float4*)&b3[tn*4];
  float4 w4v = *(const float4*)&w4[tn*4];
  float p = fmaxf(a0 + b3v.x, 0.f) * w4v.x
          + fmaxf(a1 + b3v.y, 0.f) * w4v.y
          + fmaxf(a2 + b3v.z, 0.f) * w4v.z
          + fmaxf(a3 + b3v.w, 0.f) * w4v.w;
  red[tid] = p;
  __syncthreads();
  if (tid < 16) {
    float s = 0.f;
    #pragma unroll
    for (int i = 0; i < 16; ++i) s += red[i*16 + tid];
    out[m0 + tid] = s + b4[0];
  }
}

extern "C" void kernel_launch(void* const* d_in, const int* in_sizes, int n_in,
                              void* d_out, int out_size, void* d_ws, size_t ws_size,
                              hipStream_t stream) {
  const float* x    = (const float*)d_in[0];
  const float* w1   = (const float*)d_in[1];
  const float* b1   = (const float*)d_in[2];
  const float* chw  = (const float*)d_in[3];
  const float* chb  = (const float*)d_in[4];
  const float* gnw  = (const float*)d_in[5];
  const float* gnb  = (const float*)d_in[6];
  const float* wq   = (const float*)d_in[7];
  const float* bq   = (const float*)d_in[8];
  const float* wk   = (const float*)d_in[9];
  const float* bk   = (const float*)d_in[10];
  const float* wv   = (const float*)d_in[11];
  const float* bv   = (const float*)d_in[12];
  const float* wp   = (const float*)d_in[13];
  const float* bp   = (const float*)d_in[14];
  const float* ch2w = (const float*)d_in[15];
  const float* ch2b = (const float*)d_in[16];
  const float* w2   = (const float*)d_in[17];
  const float* b2   = (const float*)d_in[18];
  const float* w3   = (const float*)d_in[19];
  const float* b3   = (const float*)d_in[20];
  const float* w4   = (const float*)d_in[21];
  const float* b4   = (const float*)d_in[22];
  (void)bk; (void)in_sizes; (void)n_in; (void)out_size; (void)ws_size;

  float* ws = (float*)d_ws;
  float* c2 = ws + WS_C2;
  float* z1 = ws + WS_Z1;
  float* out = (float*)d_out;

  hipLaunchKernelGGL(k0_precompute, dim3(34), dim3(256), 0, stream,
                     wq, bq, wk, bk, wv, bv, wp, bp, ws);
  hipLaunchKernelGGL(k1_sample, dim3(4096), dim3(384), 0, stream,
                     x, w1, b1, chw, chb, gnw, gnb, ch2w, ch2b, ws, c2);
  hipLaunchKernelGGL(k2_fc1, dim3(32, 12), dim3(256), 0, stream, c2, w2, b2, z1);
  hipLaunchKernelGGL(k3_fc23, dim3(256), dim3(256), 0, stream, z1, w3, b3, w4, b4, out);
}